// Round 7
// baseline (206.702 us; speedup 1.0000x reference)
//
#include <hip/hip_runtime.h>
#include <cmath>

#define SEQ    2048
#define DMODEL 1024
#define NHEADS 16
#define DK     64
#define MROWS  4096   // B*S
#define KBUF   4096   // flash LDS double-buffer offset (64*64 shorts)

typedef __bf16 bf16x8 __attribute__((ext_vector_type(8)));
typedef float  f32x4  __attribute__((ext_vector_type(4)));
typedef short  s16x4  __attribute__((ext_vector_type(4)));

__device__ __forceinline__ unsigned short f2bf(float f) {
    union { float f; unsigned u; } v; v.f = f;
    unsigned r = v.u + 0x7fffu + ((v.u >> 16) & 1u);   // RNE
    return (unsigned short)(r >> 16);
}

__device__ __forceinline__ void async16(const unsigned short* g, unsigned short* l) {
    __builtin_amdgcn_global_load_lds(
        (const __attribute__((address_space(1))) unsigned int*)(g),
        (__attribute__((address_space(3))) unsigned int*)(l),
        16, 0, 0);
}

__device__ __forceinline__ uint4 cvt8(float4 a, float4 b) {
    union { unsigned short us[8]; uint4 v; } o;
    o.us[0]=f2bf(a.x); o.us[1]=f2bf(a.y); o.us[2]=f2bf(a.z); o.us[3]=f2bf(a.w);
    o.us[4]=f2bf(b.x); o.us[5]=f2bf(b.y); o.us[6]=f2bf(b.z); o.us[7]=f2bf(b.w);
    return o.v;
}

// XOR-granule swizzle: pitch 64 shorts, 8-short (16B) granules, granule g of
// row r lives at slot g ^ (r&7).  All flash LDS accesses map 8 lanes to each
// 4-bank group per op -> conflict-free (R13: was 5.5M conflict cycles).
__device__ __forceinline__ int swz64(int row, int col) {
    return (row << 6) + ((((col >> 3) ^ row) & 7) << 3) + (col & 7);
}

// ---------------------------------------------------------------------------
// R18: 3-dispatch pipeline (was 5).  Designed experiment: five structural
// per-kernel optimizations (R13-R17) moved the 167-182us total by ZERO net;
// per-kernel rooflines sum to ~100us -> ~60-70us suspected between kernels.
// This round removes 2 dispatches to test that hypothesis with max contrast.
//
// bf16 MFMA GEMM, fused conversion: Y = A[M][1024] @ B[NCOLS][1024]^T.
// B is staged DIRECTLY from f32 weights: reg-load 2xfloat4 -> f2bf ->
// ds_write uint4 into the exact slot async16 would fill (LDS linear, source
// XOR-swizzled: row i*32+w*8+(lane>>3), col (lane&7)*8, source col gslot*8).
// Next-step loads issue right after the tile-visible barrier -> latency
// drains under MFMA.  launch_bounds(256,2): staging regs push VGPR ~180.
// MODE 1 (QKV): A staged from f32 x the same way.  cols <2048 -> RoPE ->
//   qk buf; cols >=2048 -> V^T [b][d][s].
// MODE 2 (O-proj): A final rows from ob via async16; A split rows (R17)
//   combine-on-the-fly from Opart x2 + Lp (block-uniform branch).  f32 out.
// ---------------------------------------------------------------------------
template<int TM, int TN, int NCOLS, int MODE, int MINW>
__global__ __launch_bounds__(256, MINW)
void gemm_fused(const unsigned short* __restrict__ Abf,  // MODE2: ob
                const float* __restrict__ Af,            // MODE1: x
                const float* __restrict__ B0,            // MODE1: wq / MODE2: wo
                const float* __restrict__ B1,            // MODE1: wk
                const float* __restrict__ B2,            // MODE1: wv
                void* __restrict__ Yqk,                  // MODE1: qk / MODE2: out
                unsigned short* __restrict__ Yvt,        // MODE1: vt
                const float* __restrict__ OpP,           // MODE2: O partials
                const float* __restrict__ LpP)           // MODE2: l partials
{
    constexpr int AINST = TM / 32;
    constexpr int BINST = TN / 32;
    constexpr int MT    = TM / 32;
    constexpr int NT    = TN / 32;

    __shared__ unsigned short As[TM * 64];
    __shared__ unsigned short Bs[TN * 64];

    const int t    = threadIdx.x;
    const int w    = t >> 6;
    const int lane = t & 63;
    const int lq   = lane >> 4;
    const int ln   = lane & 15;
    const int m0   = blockIdx.y * TM;
    const int n0   = blockIdx.x * TN;

    const int mrow0 = (w & 1) * (TM / 2);
    const int ncol0 = (w >> 1) * (TN / 2);

    const int srow  = w*8 + (lane >> 3);
    const int gslot = (lane & 7) ^ (lane >> 3);
    const int lrow8 = (lane & 7) * 8;          // LDS col for this lane's granule

    // --- B source (f32 weights); TN tiles never cross the 1024 boundaries
    const float* Bsrc; int nb;
    if constexpr (MODE == 1) {
        Bsrc = (n0 < 1024) ? B0 : (n0 < 2048) ? B1 : B2;
        nb   = n0 & 1023;
    } else { Bsrc = B0; nb = n0; }

    const float* gBf[BINST];
    #pragma unroll
    for (int i = 0; i < BINST; ++i)
        gBf[i] = Bsrc + (size_t)(nb + i*32 + srow) * 1024 + gslot*8;

    const float* gAf[AINST];
    const unsigned short* gA[AINST]; unsigned short* lA[AINST];
    #pragma unroll
    for (int i = 0; i < AINST; ++i) {
        if constexpr (MODE == 1)
            gAf[i] = Af + (size_t)(m0 + i*32 + srow) * 1024 + gslot*8;
        else {
            gA[i] = Abf + (size_t)(m0 + i*32 + srow) * 1024 + gslot*8;
            lA[i] = As + (i*32 + w*8) * 64;
        }
    }

    // ---- MODE 2 split-region state (R17 combine-on-the-fly) ----
    const bool partial = (MODE == 2) && ((m0 & 2047) >= 1024);
    int  pbase[AINST], plbase[AINST];
    float4 r0a[AINST], r0b[AINST], r1a[AINST], r1b[AINST];
    float  lva[AINST], lvb[AINST];
    if constexpr (MODE == 2) {
        #pragma unroll
        for (int i = 0; i < AINST; ++i) {
            const int row = m0 + i*32 + srow;
            const int b   = row >> 11;
            const int s   = row & 2047;
            const int ipp = 31 - (s >> 6);     // valid only when partial
            const int q   = s & 63;
            pbase[i]  = (b*256 + ipp)*4096 + q*64 + gslot*8;
            plbase[i] = (b*256 + ipp)*64 + q;
        }
    }
    auto pload = [&](int kk) {     // kk = k0 value (hd = kk/64 folded in)
        #pragma unroll
        for (int i = 0; i < AINST; ++i) {
            const float* p0 = OpP + pbase[i] + kk*1024;
            r0a[i] = *(const float4*)p0;
            r0b[i] = *(const float4*)(p0 + 4);
            const float* p1 = p0 + 2097152;
            r1a[i] = *(const float4*)p1;
            r1b[i] = *(const float4*)(p1 + 4);
            lva[i] = LpP[plbase[i] + kk*16];
            lvb[i] = LpP[32768 + plbase[i] + kk*16];
        }
    };

    // ---- f32 staging registers ----
    float4 a0[AINST], a1[AINST], b0r[BINST], b1r[BINST];
    auto loadB = [&](int kk) {
        #pragma unroll
        for (int i = 0; i < BINST; ++i) {
            b0r[i] = *(const float4*)(gBf[i] + kk);
            b1r[i] = *(const float4*)(gBf[i] + kk + 4);
        }
    };
    auto loadA = [&](int kk) {
        if constexpr (MODE == 1) {
            #pragma unroll
            for (int i = 0; i < AINST; ++i) {
                a0[i] = *(const float4*)(gAf[i] + kk);
                a1[i] = *(const float4*)(gAf[i] + kk + 4);
            }
        } else {
            if (partial) pload(kk);            // final rows: async16 in store
        }
    };

    f32x4 acc[MT][NT];
    #pragma unroll
    for (int mt = 0; mt < MT; ++mt)
        #pragma unroll
        for (int nt = 0; nt < NT; ++nt)
            #pragma unroll
            for (int r = 0; r < 4; ++r) acc[mt][nt][r] = 0.0f;

    const int fsw = (ln & 7);

    loadA(0); loadB(0);                        // prologue prefetch

    for (int k0 = 0; k0 < 1024; k0 += 64) {
        __syncthreads();                       // prev-tile readers done
        // ---- store window: convert + ds_write (A then B) ----
        if constexpr (MODE == 1) {
            #pragma unroll
            for (int i = 0; i < AINST; ++i)
                *(uint4*)&As[(i*32 + srow)*64 + lrow8] = cvt8(a0[i], a1[i]);
        } else {
            if (partial) {
                #pragma unroll
                for (int i = 0; i < AINST; ++i) {
                    const float inv = 1.0f / (lva[i] + lvb[i]);
                    union { unsigned short us[8]; uint4 v4; } o;
                    o.us[0] = f2bf((r0a[i].x + r1a[i].x) * inv);
                    o.us[1] = f2bf((r0a[i].y + r1a[i].y) * inv);
                    o.us[2] = f2bf((r0a[i].z + r1a[i].z) * inv);
                    o.us[3] = f2bf((r0a[i].w + r1a[i].w) * inv);
                    o.us[4] = f2bf((r0b[i].x + r1b[i].x) * inv);
                    o.us[5] = f2bf((r0b[i].y + r1b[i].y) * inv);
                    o.us[6] = f2bf((r0b[i].z + r1b[i].z) * inv);
                    o.us[7] = f2bf((r0b[i].w + r1b[i].w) * inv);
                    *(uint4*)&As[(i*32 + srow)*64 + lrow8] = o.v4;
                }
            } else {
                #pragma unroll
                for (int i = 0; i < AINST; ++i) async16(gA[i] + k0, lA[i]);
            }
        }
        #pragma unroll
        for (int i = 0; i < BINST; ++i)
            *(uint4*)&Bs[(i*32 + srow)*64 + lrow8] = cvt8(b0r[i], b1r[i]);
        __syncthreads();                       // tile visible
        if (k0 < 960) { loadA(k0 + 64); loadB(k0 + 64); }   // drains under MFMA
        #pragma unroll
        for (int kh = 0; kh < 2; ++kh) {
            const int g  = kh*4 + lq;
            const int ps = (g ^ fsw) * 8;
            bf16x8 af[MT], bf[NT];
            #pragma unroll
            for (int mt = 0; mt < MT; ++mt)
                af[mt] = *(const bf16x8*)&As[(mrow0 + mt*16 + ln)*64 + ps];
            #pragma unroll
            for (int nt = 0; nt < NT; ++nt)
                bf[nt] = *(const bf16x8*)&Bs[(ncol0 + nt*16 + ln)*64 + ps];
            #pragma unroll
            for (int mt = 0; mt < MT; ++mt)
                #pragma unroll
                for (int nt = 0; nt < NT; ++nt)
                    acc[mt][nt] = __builtin_amdgcn_mfma_f32_16x16x32_bf16(
                                      af[mt], bf[nt], acc[mt][nt], 0, 0, 0);
        }
    }

    if constexpr (MODE == 2) {
        float* Yf = (float*)Yqk;
        #pragma unroll
        for (int nt = 0; nt < NT; ++nt) {
            const int col = n0 + ncol0 + nt*16 + ln;
            #pragma unroll
            for (int mt = 0; mt < MT; ++mt) {
                const int row0 = m0 + mrow0 + mt*16 + lq*4;
                #pragma unroll
                for (int r = 0; r < 4; ++r)
                    Yf[(size_t)(row0 + r) * NCOLS + col] = acc[mt][nt][r];
            }
        }
    } else if (n0 < 2048) {
        // QK region: RoPE via rotation recurrence, bf16 row-major LD 2048
        unsigned short* Yb = (unsigned short*)Yqk;
        const float LOG_T = 9.210340371976184f / 32.0f;
        #pragma unroll
        for (int nt = 0; nt < NT; ++nt) {
            const int col = n0 + ncol0 + nt*16 + ln;
            const float fr = __expf(-(float)((col & 63) >> 1) * LOG_T);
            float sd, cd;
            __sincosf(fr, &sd, &cd);           // per-row rotation delta
            #pragma unroll
            for (int mt = 0; mt < MT; ++mt) {
                const int row0 = m0 + mrow0 + mt*16 + lq*4;
                float sn, cs;
                __sincosf((float)(row0 & (SEQ - 1)) * fr, &sn, &cs);
                #pragma unroll
                for (int r = 0; r < 4; ++r) {
                    const float v = acc[mt][nt][r];
                    const float p = __shfl_xor(v, 1);
                    const float outv = ((ln & 1) == 0) ? (v*cs - p*sn) : (p*sn + v*cs);
                    Yb[(size_t)(row0 + r) * 2048 + col] = f2bf(outv);
                    const float cs2 = cs*cd - sn*sd;   // rotate angle by fr
                    sn = sn*cd + cs*sd;
                    cs = cs2;
                }
            }
        }
    } else {
        // V region: write transposed [b][d][s]; lane's 4 rows contiguous in s
        #pragma unroll
        for (int nt = 0; nt < NT; ++nt) {
            const int d = (n0 - 2048) + ncol0 + nt*16 + ln;
            #pragma unroll
            for (int mt = 0; mt < MT; ++mt) {
                const int row0 = m0 + mrow0 + mt*16 + lq*4;
                const int b = row0 >> 11;
                const int s = row0 & 2047;
                ushort4 o;
                o.x = f2bf(acc[mt][nt][0]); o.y = f2bf(acc[mt][nt][1]);
                o.z = f2bf(acc[mt][nt][2]); o.w = f2bf(acc[mt][nt][3]);
                *(ushort4*)&Yvt[((size_t)b*1024 + d) * 2048 + s] = o;
            }
        }
    }
}

// ---------------------------------------------------------------------------
// R15 flash core: double-buffered K/V LDS, ONE barrier per KV tile.
// Iter kt: write tile kt+1 -> buf[cur^1], prefetch regs kt+2, compute on
// buf[cur], barrier, swap.  Q staged in buf1 (reads drained by 2nd prologue
// barrier).  Max-free softmax -> partials are pure sums.
// ---------------------------------------------------------------------------
__device__ __forceinline__ float flash_core(
    const unsigned short* __restrict__ Qrow,   // Q base of this q-tile (LD 2048)
    const unsigned short* __restrict__ Kgb,    // K base for this b (LD 2048)
    const unsigned short* __restrict__ Vgb,    // V^T base for this (b,head)
    unsigned short* Kt, unsigned short* Vt,    // each 2 x 64 x 64
    const int qb, const int kt0, const int kt1,   // kt range inclusive; kt1<kt0 => empty
    const int t, const int w, const int lq, const int ln,
    f32x4 (&oacc)[4])
{
    const int sr = t >> 2;            // staging row 0..63
    const int sc = (t & 3) * 16;      // staging col 0,16,32,48
    const int ks = t & 3;             // this thread's key-subtile for V staging
    const float SCALE2 = 0.125f * 1.4426950408889634f;   // 1/sqrt(dk) * log2e
    const bool any = (kt0 <= kt1);

    {   // stage Q tile -> Kt buf1 (first K-write to buf1 is iter kt0+1)
        const unsigned short* qp = Qrow + (size_t)sr * 2048 + sc;
        *(float4*)&Kt[KBUF + swz64(sr, sc)]     = *(const float4*)qp;
        *(float4*)&Kt[KBUF + swz64(sr, sc + 8)] = *(const float4*)(qp + 8);
    }
    float4 kA, kB, vA, vB;
    if (any) {   // preload first K/V^T tile into registers
        const unsigned short* kp = Kgb + (size_t)(kt0*64 + sr) * 2048 + sc;
        kA = *(const float4*)kp;  kB = *(const float4*)(kp + 8);
        const unsigned short* vp = Vgb + (size_t)sr * 2048 + kt0*64 + sc;
        vA = *(const float4*)vp;  vB = *(const float4*)(vp + 8);
    }
    __syncthreads();                    // Q visible
    const bf16x8 qf0 = *(const bf16x8*)&Kt[KBUF + swz64(w*16 + ln, lq*8)];
    const bf16x8 qf1 = *(const bf16x8*)&Kt[KBUF + swz64(w*16 + ln, 32 + lq*8)];

    if (any) {   // write tile kt0 -> buf0 (disjoint from Q reads in buf1)
        *(float4*)&Kt[swz64(sr, sc)]     = kA;
        *(float4*)&Kt[swz64(sr, sc + 8)] = kB;
        const ushort4* va4 = (const ushort4*)&vA;
        const ushort4* vb4 = (const ushort4*)&vB;
        *(ushort4*)&Vt[swz64(sr, ks*4 +  0)] = va4[0];
        *(ushort4*)&Vt[swz64(sr, ks*4 + 16)] = va4[1];
        *(ushort4*)&Vt[swz64(sr, ks*4 + 32)] = vb4[0];
        *(ushort4*)&Vt[swz64(sr, ks*4 + 48)] = vb4[1];
        if (kt0 < kt1) {                // preload regs for kt0+1
            const unsigned short* kp = Kgb + (size_t)((kt0+1)*64 + sr) * 2048 + sc;
            kA = *(const float4*)kp;  kB = *(const float4*)(kp + 8);
            const unsigned short* vp = Vgb + (size_t)sr * 2048 + (kt0+1)*64 + sc;
            vA = *(const float4*)vp;  vB = *(const float4*)(vp + 8);
        }
    }

    #pragma unroll
    for (int dt = 0; dt < 4; ++dt)
        #pragma unroll
        for (int r = 0; r < 4; ++r) oacc[dt][r] = 0.0f;
    float l_r = 0.0f;
    const int qg = qb*64 + w*16 + ln;

    __syncthreads();                    // buf0 visible; qf reads drained

    int cur = 0;
    for (int kt = kt0; kt <= kt1; ++kt) {
        const int co = cur ? KBUF : 0;      // compute buffer
        const int no = cur ? 0 : KBUF;      // next-tile buffer

        if (kt < kt1) {     // stage tile kt+1 (readers drained by barrier kt-1)
            *(float4*)&Kt[no + swz64(sr, sc)]     = kA;
            *(float4*)&Kt[no + swz64(sr, sc + 8)] = kB;
            const ushort4* va4 = (const ushort4*)&vA;
            const ushort4* vb4 = (const ushort4*)&vB;
            *(ushort4*)&Vt[no + swz64(sr, ks*4 +  0)] = va4[0];
            *(ushort4*)&Vt[no + swz64(sr, ks*4 + 16)] = va4[1];
            *(ushort4*)&Vt[no + swz64(sr, ks*4 + 32)] = vb4[0];
            *(ushort4*)&Vt[no + swz64(sr, ks*4 + 48)] = vb4[1];
            if (kt + 1 < kt1) {             // prefetch regs for kt+2
                const unsigned short* kp = Kgb + (size_t)((kt+2)*64 + sr) * 2048 + sc;
                kA = *(const float4*)kp;  kB = *(const float4*)(kp + 8);
                const unsigned short* vp = Vgb + (size_t)sr * 2048 + (kt+2)*64 + sc;
                vA = *(const float4*)vp;  vB = *(const float4*)(vp + 8);
            }
        }

        // --- S^T = K Q^T  (reads buf[cur])
        f32x4 sacc[4];
        #pragma unroll
        for (int nt = 0; nt < 4; ++nt) {
            #pragma unroll
            for (int r = 0; r < 4; ++r) sacc[nt][r] = 0.0f;
            bf16x8 kf0 = *(const bf16x8*)&Kt[co + swz64(nt*16 + ln, lq*8)];
            bf16x8 kf1 = *(const bf16x8*)&Kt[co + swz64(nt*16 + ln, 32 + lq*8)];
            sacc[nt] = __builtin_amdgcn_mfma_f32_16x16x32_bf16(kf0, qf0, sacc[nt], 0, 0, 0);
            sacc[nt] = __builtin_amdgcn_mfma_f32_16x16x32_bf16(kf1, qf1, sacc[nt], 0, 0, 0);
        }

        // --- max-free softmax: p = exp2(min(s*scale, 50)); no cross-lane
        float p[16];
        if (kt == qb) {                     // diag tile: causal mask
            #pragma unroll
            for (int nt = 0; nt < 4; ++nt)
                #pragma unroll
                for (int r = 0; r < 4; ++r) {
                    float s = fminf(sacc[nt][r] * SCALE2, 50.0f);
                    if (kt*64 + nt*16 + lq*4 + r > qg) s = -INFINITY;
                    p[nt*4 + r] = __builtin_amdgcn_exp2f(s);
                }
        } else {
            #pragma unroll
            for (int i2 = 0; i2 < 16; ++i2) {
                const int nt = i2 >> 2, r = i2 & 3;
                p[i2] = __builtin_amdgcn_exp2f(fminf(sacc[nt][r] * SCALE2, 50.0f));
            }
        }
        float sum = 0.0f;
        #pragma unroll
        for (int i2 = 0; i2 < 16; ++i2) sum += p[i2];
        l_r += sum;

        // --- pack P^T (round-half-up via +0x8000, pack with v_perm)
        s16x4 pf[4];
        #pragma unroll
        for (int kk = 0; kk < 4; ++kk) {
            union { float f; unsigned u; } c0, c1, c2, c3;
            c0.f = p[kk*4+0]; c1.f = p[kk*4+1]; c2.f = p[kk*4+2]; c3.f = p[kk*4+3];
            unsigned lo = __builtin_amdgcn_perm(c1.u + 0x8000u, c0.u + 0x8000u, 0x07060302u);
            unsigned hi = __builtin_amdgcn_perm(c3.u + 0x8000u, c2.u + 0x8000u, 0x07060302u);
            union { unsigned u2[2]; s16x4 v; } pk;
            pk.u2[0] = lo; pk.u2[1] = hi;
            pf[kk] = pk.v;
        }

        // --- O^T += V^T P^T  (V-frags: 2 b128 per dt, reads buf[cur])
        #pragma unroll
        for (int dt = 0; dt < 4; ++dt) {
            union { bf16x8 v8; s16x4 h2[2]; } u01, u23;
            u01.v8 = *(const bf16x8*)&Vt[co + swz64(dt*16 + ln, lq*16)];
            u23.v8 = *(const bf16x8*)&Vt[co + swz64(dt*16 + ln, lq*16 + 8)];
            oacc[dt] = __builtin_amdgcn_mfma_f32_16x16x16bf16_1k(u01.h2[0], pf[0], oacc[dt], 0, 0, 0);
            oacc[dt] = __builtin_amdgcn_mfma_f32_16x16x16bf16_1k(u01.h2[1], pf[1], oacc[dt], 0, 0, 0);
            oacc[dt] = __builtin_amdgcn_mfma_f32_16x16x16bf16_1k(u23.h2[0], pf[2], oacc[dt], 0, 0, 0);
            oacc[dt] = __builtin_amdgcn_mfma_f32_16x16x16bf16_1k(u23.h2[1], pf[3], oacc[dt], 0, 0, 0);
        }

        __syncthreads();    // buf[no] visible; buf[cur] readers drained
        cur ^= 1;
    }

    l_r += __shfl_xor(l_r, 16);
    l_r += __shfl_xor(l_r, 32);
    return l_r;
}

// ---------------------------------------------------------------------------
// R13 flash: balanced split.  blockIdx.y = pair*2 + half.  For pair i:
//   h0: q-tile 31-i, KV tiles [0,16]           -> 17 tiles, partial -> buf 0
//   h1: q-tile 31-i, KV tiles [17, 31-i]       -> 15-i tiles, partial -> buf 1
//       + q-tile i full [0,i]                  -> i+1 tiles, final -> Ob
// Every block = 16-17 tile-iters.  Partials (f32, unnormalized) -> Opart;
// l partials -> Lp.
// ---------------------------------------------------------------------------
__global__ __launch_bounds__(256)
void flash_mfma_kernel(const unsigned short* __restrict__ QK,
                       const unsigned short* __restrict__ Vtg,
                       unsigned short* __restrict__ Ob,
                       float* __restrict__ Opart,
                       float* __restrict__ Lp)
{
    __shared__ unsigned short Kt[2 * 64 * 64];    // dbuf: Q/K tiles / O transpose
    __shared__ unsigned short Vt[2 * 64 * 64];    // dbuf: V^T tiles (permuted+swz)

    const int t    = threadIdx.x;
    const int w    = t >> 6;
    const int lane = t & 63;
    const int lq   = lane >> 4;
    const int ln   = lane & 15;
    const int bh   = blockIdx.x;
    const int yy   = blockIdx.y;
    const int ip   = yy >> 1;          // pair index 0..15
    const int hh   = yy & 1;
    const int b    = bh >> 4;
    const int hd   = bh & 15;
    const int qA   = 31 - ip;
    const int pidx = bh * 16 + ip;

    const unsigned short* Qg  = QK + hd*DK;                              // LD 2048
    const unsigned short* Kgb = QK + 1024 + hd*DK + (size_t)b*SEQ*2048;  // LD 2048
    const unsigned short* Vgb = Vtg + ((size_t)b*1024 + hd*DK) * 2048;   // [d][s]

    f32x4 oacc[4];

    if (hh == 0) {
        float l_r = flash_core(Qg + (size_t)(b*SEQ + qA*64)*2048, Kgb, Vgb,
                               Kt, Vt, qA, 0, 16, t, w, lq, ln, oacc);
        float* Op = Opart + (size_t)pidx * 4096 + (w*16 + ln)*64;
        #pragma unroll
        for (int dt = 0; dt < 4; ++dt)
            *(f32x4*)(Op + dt*16 + lq*4) = oacc[dt];
        if (lq == 0) Lp[pidx*64 + w*16 + ln] = l_r;
    } else {
        float l_r = flash_core(Qg + (size_t)(b*SEQ + qA*64)*2048, Kgb, Vgb,
                               Kt, Vt, qA, 17, qA, t, w, lq, ln, oacc);
        float* Op = Opart + (size_t)(512 + pidx) * 4096 + (w*16 + ln)*64;
        #pragma unroll
        for (int dt = 0; dt < 4; ++dt)
            *(f32x4*)(Op + dt*16 + lq*4) = oacc[dt];
        if (lq == 0) Lp[512*64 + pidx*64 + w*16 + ln] = l_r;

        __syncthreads();                // segment-1 done before Q restage
        const int qB = ip;
        l_r = flash_core(Qg + (size_t)(b*SEQ + qB*64)*2048, Kgb, Vgb,
                         Kt, Vt, qB, 0, qB, t, w, lq, ln, oacc);
        const float linv = 1.0f / l_r;
        __syncthreads();                // last tile reads done
        #pragma unroll
        for (int dt = 0; dt < 4; ++dt)
            #pragma unroll
            for (int r = 0; r < 4; ++r)
                Kt[swz64(w*16 + ln, dt*16 + lq*4 + r)] = f2bf(oacc[dt][r] * linv);
        __syncthreads();
        const int sr  = t >> 2;
        const int sc2 = (t & 3) * 16;
        unsigned short* op = Ob + (size_t)(b*SEQ + qB*64 + sr) * DMODEL + hd*DK + sc2;
        *(float4*)(op)     = *(const float4*)&Kt[swz64(sr, sc2)];
        *(float4*)(op + 8) = *(const float4*)&Kt[swz64(sr, sc2 + 8)];
    }
}

// ---------------------------------------------------------------------------
extern "C" void kernel_launch(void* const* d_in, const int* in_sizes, int n_in,
                              void* d_out, int out_size, void* d_ws, size_t ws_size,
                              hipStream_t stream)
{
    const float* x  = (const float*)d_in[0];
    const float* Wq = (const float*)d_in[1];
    const float* Wk = (const float*)d_in[2];
    const float* Wv = (const float*)d_in[3];
    const float* Wo = (const float*)d_in[4];
    float* out = (float*)d_out;

    // R18 workspace (no bf16 input copies -- conversion fused into staging):
    unsigned short* qk    = (unsigned short*)d_ws;   // 8M shorts [4096][2048]
    unsigned short* vt    = qk + 8388608;            // 4M  [2][1024][2048]
    unsigned short* ob    = vt + 4194304;            // 4M  [4096][1024]
    float*          opart = (float*)(ob + 4194304);  // 4M f32 (2x512x64x64)
    float*          lp    = opart + 4194304;         // 64K f32
    // total ~50.6 MB (ws is 256 MB per harness poison fills)

    // QKV (conversion fused): 128x128 tiles, grid (24,32) = 768 blocks
    gemm_fused<128, 128, 2048, 1, 2><<<dim3(24, 32), 256, 0, stream>>>(
        nullptr, x, Wq, Wk, Wv, qk, vt, nullptr, nullptr);

    // balanced flash: 32 bh x (16 pairs x 2 halves)
    flash_mfma_kernel<<<dim3(32, 32), 256, 0, stream>>>(qk, vt, ob, opart, lp);

    // O-proj (combine + Wo-conversion fused): 128x64 tiles, (16,32) = 512
    gemm_fused<128, 64, 1024, 2, 2><<<dim3(16, 32), 256, 0, stream>>>(
        ob, nullptr, Wo, nullptr, nullptr, out, nullptr, opart, lp);
}

// Round 8
// 180.964 us; speedup vs baseline: 1.1422x; 1.1422x over previous
//
#include <hip/hip_runtime.h>
#include <cmath>

#define SEQ    2048
#define DMODEL 1024
#define NHEADS 16
#define DK     64
#define MROWS  4096   // B*S
#define KBUF   4096   // flash LDS double-buffer offset (64*64 shorts)

typedef __bf16 bf16x8 __attribute__((ext_vector_type(8)));
typedef float  f32x4  __attribute__((ext_vector_type(4)));
typedef short  s16x4  __attribute__((ext_vector_type(4)));

__device__ __forceinline__ unsigned short f2bf(float f) {
    union { float f; unsigned u; } v; v.f = f;
    unsigned r = v.u + 0x7fffu + ((v.u >> 16) & 1u);   // RNE
    return (unsigned short)(r >> 16);
}

__device__ __forceinline__ void async16(const unsigned short* g, unsigned short* l) {
    __builtin_amdgcn_global_load_lds(
        (const __attribute__((address_space(1))) unsigned int*)(g),
        (__attribute__((address_space(3))) unsigned int*)(l),
        16, 0, 0);
}

// XOR-granule swizzle: pitch 64 shorts, 8-short (16B) granules, granule g of
// row r lives at slot g ^ (r&7).  All flash LDS b128 accesses are granule-
// aligned -> conflict-free.  R19: the STAGING side now produces this layout
// via per-lane swizzled-address async16 (LDS dest linear, src granule XOR'd)
// -- guide m173: global src of global_load_lds IS per-lane.
__device__ __forceinline__ int swz64(int row, int col) {
    return (row << 6) + ((((col >> 3) ^ row) & 7) << 3) + (col & 7);
}

// ---------------------------------------------------------------------------
// fp32 -> bf16 conversion of x, Wq|Wk|Wv (packed), Wo  (restored in R19:
// R7 PM showed fused f32 staging = 71.7us QKV, FETCH 80MB, MfmaUtil 14% --
// strictly worse than convert+async16 which held QKV < 43us in R3-R6).
// ---------------------------------------------------------------------------
__global__ __launch_bounds__(256)
void convert_kernel(const float* __restrict__ x,
                    const float* __restrict__ wq, const float* __restrict__ wk,
                    const float* __restrict__ wv, const float* __restrict__ wo,
                    unsigned short* __restrict__ xb,
                    unsigned short* __restrict__ wqkvb,
                    unsigned short* __restrict__ wob)
{
    const unsigned e = (blockIdx.x * 256u + threadIdx.x) * 8u;
    const float* src; unsigned short* dst; unsigned off;
    if      (e < 4194304u) { src = x;  dst = xb;             off = e;            }
    else if (e < 5242880u) { src = wq; dst = wqkvb;          off = e - 4194304u; }
    else if (e < 6291456u) { src = wk; dst = wqkvb+1048576u; off = e - 5242880u; }
    else if (e < 7340032u) { src = wv; dst = wqkvb+2097152u; off = e - 6291456u; }
    else                   { src = wo; dst = wob;            off = e - 7340032u; }
    float4 a = *(const float4*)(src + off);
    float4 b = *(const float4*)(src + off + 4);
    ushort4 u0, u1;
    u0.x=f2bf(a.x); u0.y=f2bf(a.y); u0.z=f2bf(a.z); u0.w=f2bf(a.w);
    u1.x=f2bf(b.x); u1.y=f2bf(b.y); u1.z=f2bf(b.z); u1.w=f2bf(b.w);
    *(ushort4*)(dst + off)     = u0;
    *(ushort4*)(dst + off + 4) = u1;
}

// ---------------------------------------------------------------------------
// bf16 MFMA GEMM: Y = A[M][1024] @ B[NCOLS][1024]^T.  TM x TN tiles, BK=64,
// single-buffered async16 (m97 structure).  QKV: 128x128 @ 3/CU.
// O-proj: 128x64 @ 2/CU.
// MODE 1 (QKV): cols <2048 -> RoPE (rotation recurrence) -> qk buf;
//   cols >=2048 -> V^T written PRE-PERMUTED (R19): within each 64-col kt
//   block, col' = 16*((s>>2)&3) + 4*((s>>4)&3) + (s&3), so flash can stage
//   V with linear-dest async16 + XOR'd source granule.
// MODE 2 (O-proj): A final rows via async16 from ob; A split rows combine-
//   on-the-fly from Opart x2 + Lp (block-uniform branch).  f32 out.
// ---------------------------------------------------------------------------
template<int TM, int TN, int NCOLS, int MODE, int MINW>
__global__ __launch_bounds__(256, MINW)
void gemm_mfma_bt(const unsigned short* __restrict__ A,
                  const unsigned short* __restrict__ B,
                  void* __restrict__ Yqk,
                  unsigned short* __restrict__ Yvt,
                  const float* __restrict__ OpP,   // MODE 2: partials base
                  const float* __restrict__ LpP)   // MODE 2: l partials base
{
    constexpr int AINST = TM / 32;
    constexpr int BINST = TN / 32;
    constexpr int MT    = TM / 32;
    constexpr int NT    = TN / 32;

    __shared__ unsigned short As[TM * 64];
    __shared__ unsigned short Bs[TN * 64];

    const int t    = threadIdx.x;
    const int w    = t >> 6;
    const int lane = t & 63;
    const int lq   = lane >> 4;
    const int ln   = lane & 15;
    const int m0   = blockIdx.y * TM;
    const int n0   = blockIdx.x * TN;

    const int mrow0 = (w & 1) * (TM / 2);
    const int ncol0 = (w >> 1) * (TN / 2);

    const int srow  = w*8 + (lane >> 3);
    const int gslot = (lane & 7) ^ (lane >> 3);

    const unsigned short* gA[AINST]; unsigned short* lA[AINST];
    #pragma unroll
    for (int i = 0; i < AINST; ++i) {
        gA[i] = A + (size_t)(m0 + i*32 + srow) * 1024 + gslot*8;
        lA[i] = As + (i*32 + w*8) * 64;
    }
    const unsigned short* gB[BINST]; unsigned short* lB[BINST];
    #pragma unroll
    for (int i = 0; i < BINST; ++i) {
        gB[i] = B + (size_t)(n0 + i*32 + srow) * 1024 + gslot*8;
        lB[i] = Bs + (i*32 + w*8) * 64;
    }

    // ---- MODE 2 split-region state (combine-on-the-fly) ----
    const bool partial = (MODE == 2) && ((m0 & 2047) >= 1024);
    int  pbase[AINST], plbase[AINST];
    float4 r0a[AINST], r0b[AINST], r1a[AINST], r1b[AINST];
    float  lva[AINST], lvb[AINST];
    if constexpr (MODE == 2) {
        #pragma unroll
        for (int i = 0; i < AINST; ++i) {
            const int row = m0 + i*32 + srow;
            const int b   = row >> 11;
            const int s   = row & 2047;
            const int ipp = 31 - (s >> 6);     // valid only when partial
            const int q   = s & 63;
            pbase[i]  = (b*256 + ipp)*4096 + q*64 + gslot*8;
            plbase[i] = (b*256 + ipp)*64 + q;
        }
    }
    auto pload = [&](int kk) {
        #pragma unroll
        for (int i = 0; i < AINST; ++i) {
            const float* p0 = OpP + pbase[i] + kk*1024;
            r0a[i] = *(const float4*)p0;
            r0b[i] = *(const float4*)(p0 + 4);
            const float* p1 = p0 + 2097152;
            r1a[i] = *(const float4*)p1;
            r1b[i] = *(const float4*)(p1 + 4);
            lva[i] = LpP[plbase[i] + kk*16];
            lvb[i] = LpP[32768 + plbase[i] + kk*16];
        }
    };
    if constexpr (MODE == 2) { if (partial) pload(0); }

    f32x4 acc[MT][NT];
    #pragma unroll
    for (int mt = 0; mt < MT; ++mt)
        #pragma unroll
        for (int nt = 0; nt < NT; ++nt)
            #pragma unroll
            for (int r = 0; r < 4; ++r) acc[mt][nt][r] = 0.0f;

    const int fsw = (ln & 7);

    for (int k0 = 0; k0 < 1024; k0 += 64) {
        __syncthreads();
        if constexpr (MODE == 2) {
            if (partial) {
                #pragma unroll
                for (int i = 0; i < AINST; ++i) {
                    const float inv = 1.0f / (lva[i] + lvb[i]);
                    union { unsigned short us[8]; uint4 v4; } o;
                    o.us[0] = f2bf((r0a[i].x + r1a[i].x) * inv);
                    o.us[1] = f2bf((r0a[i].y + r1a[i].y) * inv);
                    o.us[2] = f2bf((r0a[i].z + r1a[i].z) * inv);
                    o.us[3] = f2bf((r0a[i].w + r1a[i].w) * inv);
                    o.us[4] = f2bf((r0b[i].x + r1b[i].x) * inv);
                    o.us[5] = f2bf((r0b[i].y + r1b[i].y) * inv);
                    o.us[6] = f2bf((r0b[i].z + r1b[i].z) * inv);
                    o.us[7] = f2bf((r0b[i].w + r1b[i].w) * inv);
                    *(uint4*)&As[(i*32 + srow)*64 + (lane & 7)*8] = o.v4;
                }
            } else {
                #pragma unroll
                for (int i = 0; i < AINST; ++i) async16(gA[i] + k0, lA[i]);
            }
        } else {
            #pragma unroll
            for (int i = 0; i < AINST; ++i) async16(gA[i] + k0, lA[i]);
        }
        #pragma unroll
        for (int i = 0; i < BINST; ++i) async16(gB[i] + k0, lB[i]);
        __syncthreads();
        if constexpr (MODE == 2) {
            if (partial && k0 < 960) pload(k0 + 64);   // drains under MFMA
        }
        #pragma unroll
        for (int kh = 0; kh < 2; ++kh) {
            const int g  = kh*4 + lq;
            const int ps = (g ^ fsw) * 8;
            bf16x8 af[MT], bf[NT];
            #pragma unroll
            for (int mt = 0; mt < MT; ++mt)
                af[mt] = *(const bf16x8*)&As[(mrow0 + mt*16 + ln)*64 + ps];
            #pragma unroll
            for (int nt = 0; nt < NT; ++nt)
                bf[nt] = *(const bf16x8*)&Bs[(ncol0 + nt*16 + ln)*64 + ps];
            #pragma unroll
            for (int mt = 0; mt < MT; ++mt)
                #pragma unroll
                for (int nt = 0; nt < NT; ++nt)
                    acc[mt][nt] = __builtin_amdgcn_mfma_f32_16x16x32_bf16(
                                      af[mt], bf[nt], acc[mt][nt], 0, 0, 0);
        }
    }

    if constexpr (MODE == 2) {
        float* Yf = (float*)Yqk;
        #pragma unroll
        for (int nt = 0; nt < NT; ++nt) {
            const int col = n0 + ncol0 + nt*16 + ln;
            #pragma unroll
            for (int mt = 0; mt < MT; ++mt) {
                const int row0 = m0 + mrow0 + mt*16 + lq*4;
                #pragma unroll
                for (int r = 0; r < 4; ++r)
                    Yf[(size_t)(row0 + r) * NCOLS + col] = acc[mt][nt][r];
            }
        }
    } else if (n0 < 2048) {
        // QK region: RoPE via rotation recurrence, bf16 row-major LD 2048
        unsigned short* Yb = (unsigned short*)Yqk;
        const float LOG_T = 9.210340371976184f / 32.0f;
        #pragma unroll
        for (int nt = 0; nt < NT; ++nt) {
            const int col = n0 + ncol0 + nt*16 + ln;
            const float fr = __expf(-(float)((col & 63) >> 1) * LOG_T);
            float sd, cd;
            __sincosf(fr, &sd, &cd);           // per-row rotation delta
            #pragma unroll
            for (int mt = 0; mt < MT; ++mt) {
                const int row0 = m0 + mrow0 + mt*16 + lq*4;
                float sn, cs;
                __sincosf((float)(row0 & (SEQ - 1)) * fr, &sn, &cs);
                #pragma unroll
                for (int r = 0; r < 4; ++r) {
                    const float v = acc[mt][nt][r];
                    const float p = __shfl_xor(v, 1);
                    const float outv = ((ln & 1) == 0) ? (v*cs - p*sn) : (p*sn + v*cs);
                    Yb[(size_t)(row0 + r) * 2048 + col] = f2bf(outv);
                    const float cs2 = cs*cd - sn*sd;   // rotate angle by fr
                    sn = sn*cd + cs*sd;
                    cs = cs2;
                }
            }
        }
    } else {
        // V region: write V^T pre-permuted within each 64-col kt block:
        // col' = 16*((s>>2)&3) + 4*((s>>4)&3) + (s&3).  4 consecutive s
        // (e=0..3) stay contiguous -> same ushort4 write pattern as before.
        #pragma unroll
        for (int nt = 0; nt < NT; ++nt) {
            const int d = (n0 - 2048) + ncol0 + nt*16 + ln;
            #pragma unroll
            for (int mt = 0; mt < MT; ++mt) {
                const int row0 = m0 + mrow0 + mt*16 + lq*4;
                const int b = row0 >> 11;
                const int s = row0 & 2047;
                const int sp = (s & ~63) + 16*((s >> 2) & 3) + 4*((s >> 4) & 3);
                ushort4 o;
                o.x = f2bf(acc[mt][nt][0]); o.y = f2bf(acc[mt][nt][1]);
                o.z = f2bf(acc[mt][nt][2]); o.w = f2bf(acc[mt][nt][3]);
                *(ushort4*)&Yvt[((size_t)b*1024 + d) * 2048 + sp] = o;
            }
        }
    }
}

// ---------------------------------------------------------------------------
// R19 flash core: K/V/Q staged via per-lane swizzled-address async16 into
// linear LDS (content identical to the old swz64 reg-staging; read side
// unchanged).  Double-buffered, ONE barrier per KV tile, no reg-staging
// VALU, no vmcnt-coupled store window.  Max-free softmax -> pure-sum parts.
// ---------------------------------------------------------------------------
__device__ __forceinline__ float flash_core(
    const unsigned short* __restrict__ Qrow,   // Q base of this q-tile (LD 2048)
    const unsigned short* __restrict__ Kgb,    // K base for this b (LD 2048, +hd)
    const unsigned short* __restrict__ Vgb,    // V^T permuted base for (b,head)
    unsigned short* Kt, unsigned short* Vt,    // each 2 x 64 x 64
    const int qb, const int kt0, const int kt1,
    const int t, const int w, const int lq, const int ln,
    f32x4 (&oacc)[4])
{
    const int lane = t & 63;
    const int r0 = w*8 + (lane >> 3);          // op0 row (0..31)
    const int r1 = 32 + r0;                    // op1 row (32..63)
    const int sl = lane & 7;                   // linear LDS slot
    const int g0 = (sl ^ r0) & 7;              // swizzled source granule
    const int g1 = (sl ^ r1) & 7;
    const float SCALE2 = 0.125f * 1.4426950408889634f;   // 1/sqrt(dk) * log2e
    const bool any = (kt0 <= kt1);

    unsigned short* ldLo = Kt + (w*8)*64;      // wave-uniform LDS bases
    unsigned short* ldHi = Kt + (32 + w*8)*64;
    unsigned short* lvLo = Vt + (w*8)*64;
    unsigned short* lvHi = Vt + (32 + w*8)*64;

    // Q -> Kt buf1 (content = swz64 layout via source-granule XOR)
    async16(Qrow + (size_t)r0*2048 + g0*8, ldLo + KBUF);
    async16(Qrow + (size_t)r1*2048 + g1*8, ldHi + KBUF);
    if (any) {                                 // K/V tile kt0 -> buf0
        async16(Kgb + (size_t)(kt0*64 + r0)*2048 + g0*8, ldLo);
        async16(Kgb + (size_t)(kt0*64 + r1)*2048 + g1*8, ldHi);
        async16(Vgb + (size_t)r0*2048 + kt0*64 + g0*8, lvLo);
        async16(Vgb + (size_t)r1*2048 + kt0*64 + g1*8, lvHi);
    }
    __syncthreads();                           // all async16 drained
    const bf16x8 qf0 = *(const bf16x8*)&Kt[KBUF + swz64(w*16 + ln, lq*8)];
    const bf16x8 qf1 = *(const bf16x8*)&Kt[KBUF + swz64(w*16 + ln, 32 + lq*8)];

    #pragma unroll
    for (int dt = 0; dt < 4; ++dt)
        #pragma unroll
        for (int r = 0; r < 4; ++r) oacc[dt][r] = 0.0f;
    float l_r = 0.0f;
    const int qg = qb*64 + w*16 + ln;

    __syncthreads();                           // qf reads drained

    int cur = 0;
    for (int kt = kt0; kt <= kt1; ++kt) {
        const int co = cur ? KBUF : 0;
        const int no = co ^ KBUF;

        if (kt < kt1) {   // stage kt+1 -> other buffer; drains under compute
            async16(Kgb + (size_t)((kt+1)*64 + r0)*2048 + g0*8, ldLo + no);
            async16(Kgb + (size_t)((kt+1)*64 + r1)*2048 + g1*8, ldHi + no);
            async16(Vgb + (size_t)r0*2048 + (kt+1)*64 + g0*8, lvLo + no);
            async16(Vgb + (size_t)r1*2048 + (kt+1)*64 + g1*8, lvHi + no);
        }

        // --- S^T = K Q^T  (reads buf[cur])
        f32x4 sacc[4];
        #pragma unroll
        for (int nt = 0; nt < 4; ++nt) {
            #pragma unroll
            for (int r = 0; r < 4; ++r) sacc[nt][r] = 0.0f;
            bf16x8 kf0 = *(const bf16x8*)&Kt[co + swz64(nt*16 + ln, lq*8)];
            bf16x8 kf1 = *(const bf16x8*)&Kt[co + swz64(nt*16 + ln, 32 + lq*8)];
            sacc[nt] = __builtin_amdgcn_mfma_f32_16x16x32_bf16(kf0, qf0, sacc[nt], 0, 0, 0);
            sacc[nt] = __builtin_amdgcn_mfma_f32_16x16x32_bf16(kf1, qf1, sacc[nt], 0, 0, 0);
        }

        // --- max-free softmax: p = exp2(min(s*scale, 50)); no cross-lane
        float p[16];
        if (kt == qb) {                     // diag tile: causal mask
            #pragma unroll
            for (int nt = 0; nt < 4; ++nt)
                #pragma unroll
                for (int r = 0; r < 4; ++r) {
                    float s = fminf(sacc[nt][r] * SCALE2, 50.0f);
                    if (kt*64 + nt*16 + lq*4 + r > qg) s = -INFINITY;
                    p[nt*4 + r] = __builtin_amdgcn_exp2f(s);
                }
        } else {
            #pragma unroll
            for (int i2 = 0; i2 < 16; ++i2) {
                const int nt = i2 >> 2, r = i2 & 3;
                p[i2] = __builtin_amdgcn_exp2f(fminf(sacc[nt][r] * SCALE2, 50.0f));
            }
        }
        float sum = 0.0f;
        #pragma unroll
        for (int i2 = 0; i2 < 16; ++i2) sum += p[i2];
        l_r += sum;

        // --- pack P^T (round-half-up via +0x8000, pack with v_perm)
        s16x4 pf[4];
        #pragma unroll
        for (int kk = 0; kk < 4; ++kk) {
            union { float f; unsigned u; } c0, c1, c2, c3;
            c0.f = p[kk*4+0]; c1.f = p[kk*4+1]; c2.f = p[kk*4+2]; c3.f = p[kk*4+3];
            unsigned lo = __builtin_amdgcn_perm(c1.u + 0x8000u, c0.u + 0x8000u, 0x07060302u);
            unsigned hi = __builtin_amdgcn_perm(c3.u + 0x8000u, c2.u + 0x8000u, 0x07060302u);
            union { unsigned u2[2]; s16x4 v; } pk;
            pk.u2[0] = lo; pk.u2[1] = hi;
            pf[kk] = pk.v;
        }

        // --- O^T += V^T P^T  (V-frags: 2 b128 per dt, reads buf[cur])
        #pragma unroll
        for (int dt = 0; dt < 4; ++dt) {
            union { bf16x8 v8; s16x4 h2[2]; } u01, u23;
            u01.v8 = *(const bf16x8*)&Vt[co + swz64(dt*16 + ln, lq*16)];
            u23.v8 = *(const bf16x8*)&Vt[co + swz64(dt*16 + ln, lq*16 + 8)];
            oacc[dt] = __builtin_amdgcn_mfma_f32_16x16x16bf16_1k(u01.h2[0], pf[0], oacc[dt], 0, 0, 0);
            oacc[dt] = __builtin_amdgcn_mfma_f32_16x16x16bf16_1k(u01.h2[1], pf[1], oacc[dt], 0, 0, 0);
            oacc[dt] = __builtin_amdgcn_mfma_f32_16x16x16bf16_1k(u23.h2[0], pf[2], oacc[dt], 0, 0, 0);
            oacc[dt] = __builtin_amdgcn_mfma_f32_16x16x16bf16_1k(u23.h2[1], pf[3], oacc[dt], 0, 0, 0);
        }

        __syncthreads();    // buf[no] async writes visible; buf[cur] drained
        cur ^= 1;
    }

    l_r += __shfl_xor(l_r, 16);
    l_r += __shfl_xor(l_r, 32);
    return l_r;
}

// ---------------------------------------------------------------------------
// Balanced-split flash.  blockIdx.y = pair*2 + half.  For pair i:
//   h0: q-tile 31-i, KV [0,16]  -> 17 tiles, partial -> buf 0
//   h1: q-tile 31-i, KV [17,31-i] -> 15-i tiles, partial -> buf 1
//       + q-tile i full [0,i]   -> i+1 tiles, final -> Ob
// ---------------------------------------------------------------------------
__global__ __launch_bounds__(256)
void flash_mfma_kernel(const unsigned short* __restrict__ QK,
                       const unsigned short* __restrict__ Vtg,
                       unsigned short* __restrict__ Ob,
                       float* __restrict__ Opart,
                       float* __restrict__ Lp)
{
    __shared__ unsigned short Kt[2 * 64 * 64];    // dbuf: Q/K tiles / O transpose
    __shared__ unsigned short Vt[2 * 64 * 64];    // dbuf: V^T tiles (permuted)

    const int t    = threadIdx.x;
    const int w    = t >> 6;
    const int lane = t & 63;
    const int lq   = lane >> 4;
    const int ln   = lane & 15;
    const int bh   = blockIdx.x;
    const int yy   = blockIdx.y;
    const int ip   = yy >> 1;          // pair index 0..15
    const int hh   = yy & 1;
    const int b    = bh >> 4;
    const int hd   = bh & 15;
    const int qA   = 31 - ip;
    const int pidx = bh * 16 + ip;

    const unsigned short* Qg  = QK + hd*DK;                              // LD 2048
    const unsigned short* Kgb = QK + 1024 + hd*DK + (size_t)b*SEQ*2048;  // LD 2048
    const unsigned short* Vgb = Vtg + ((size_t)b*1024 + hd*DK) * 2048;   // [d][s']

    f32x4 oacc[4];

    if (hh == 0) {
        float l_r = flash_core(Qg + (size_t)(b*SEQ + qA*64)*2048, Kgb, Vgb,
                               Kt, Vt, qA, 0, 16, t, w, lq, ln, oacc);
        float* Op = Opart + (size_t)pidx * 4096 + (w*16 + ln)*64;
        #pragma unroll
        for (int dt = 0; dt < 4; ++dt)
            *(f32x4*)(Op + dt*16 + lq*4) = oacc[dt];
        if (lq == 0) Lp[pidx*64 + w*16 + ln] = l_r;
    } else {
        float l_r = flash_core(Qg + (size_t)(b*SEQ + qA*64)*2048, Kgb, Vgb,
                               Kt, Vt, qA, 17, qA, t, w, lq, ln, oacc);
        float* Op = Opart + (size_t)(512 + pidx) * 4096 + (w*16 + ln)*64;
        #pragma unroll
        for (int dt = 0; dt < 4; ++dt)
            *(f32x4*)(Op + dt*16 + lq*4) = oacc[dt];
        if (lq == 0) Lp[512*64 + pidx*64 + w*16 + ln] = l_r;

        __syncthreads();                // segment-1 done before Q restage
        const int qB = ip;
        l_r = flash_core(Qg + (size_t)(b*SEQ + qB*64)*2048, Kgb, Vgb,
                         Kt, Vt, qB, 0, qB, t, w, lq, ln, oacc);
        const float linv = 1.0f / l_r;
        __syncthreads();                // last tile reads done
        #pragma unroll
        for (int dt = 0; dt < 4; ++dt)
            #pragma unroll
            for (int r = 0; r < 4; ++r)
                Kt[swz64(w*16 + ln, dt*16 + lq*4 + r)] = f2bf(oacc[dt][r] * linv);
        __syncthreads();
        const int sr  = t >> 2;
        const int sc2 = (t & 3) * 16;
        unsigned short* op = Ob + (size_t)(b*SEQ + qB*64 + sr) * DMODEL + hd*DK + sc2;
        *(float4*)(op)     = *(const float4*)&Kt[swz64(sr, sc2)];
        *(float4*)(op + 8) = *(const float4*)&Kt[swz64(sr, sc2 + 8)];
    }
}

// ---------------------------------------------------------------------------
extern "C" void kernel_launch(void* const* d_in, const int* in_sizes, int n_in,
                              void* d_out, int out_size, void* d_ws, size_t ws_size,
                              hipStream_t stream)
{
    const float* x  = (const float*)d_in[0];
    const float* Wq = (const float*)d_in[1];
    const float* Wk = (const float*)d_in[2];
    const float* Wv = (const float*)d_in[3];
    const float* Wo = (const float*)d_in[4];
    float* out = (float*)d_out;

    unsigned short* xb    = (unsigned short*)d_ws;   //  4M shorts
    unsigned short* wqkvb = xb + 4194304;            //  3M
    unsigned short* wob   = wqkvb + 3145728;         //  1M
    unsigned short* qk    = wob + 1048576;           //  8M  [4096][2048]
    unsigned short* vt    = qk + 8388608;            //  4M  [2][1024][2048] perm
    unsigned short* ob    = vt + 4194304;            //  4M  [4096][1024]
    float*          opart = (float*)(ob + 4194304);  //  4M f32 (2x512x64x64)
    float*          lp    = opart + 4194304;         //  64K f32
    // total ~64.3 MB of the 256 MB workspace

    convert_kernel<<<4096, 256, 0, stream>>>(x, Wq, Wk, Wv, Wo, xb, wqkvb, wob);

    // QKV: 128x128 tiles, grid (24,32) = 768 blocks = 3/CU
    gemm_mfma_bt<128, 128, 2048, 1, 3><<<dim3(24, 32), 256, 0, stream>>>(
        xb, wqkvb, qk, vt, nullptr, nullptr);

    // balanced flash: 32 bh x (16 pairs x 2 halves), async16 staging
    flash_mfma_kernel<<<dim3(32, 32), 256, 0, stream>>>(qk, vt, ob, opart, lp);

    // O-proj (fused combine): 128x64 tiles, (16,32) = 512 blocks = 2/CU
    gemm_mfma_bt<128, 64, 1024, 2, 2><<<dim3(16, 32), 256, 0, stream>>>(
        ob, wob, out, nullptr, opart, lp);
}

// Round 9
// 167.249 us; speedup vs baseline: 1.2359x; 1.0820x over previous
//
#include <hip/hip_runtime.h>
#include <cmath>

#define SEQ    2048
#define DMODEL 1024
#define NHEADS 16
#define DK     64
#define MROWS  4096   // B*S
#define KBUF   4096   // flash LDS double-buffer offset (64*64 shorts)

typedef __bf16 bf16x8 __attribute__((ext_vector_type(8)));
typedef float  f32x4  __attribute__((ext_vector_type(4)));
typedef short  s16x4  __attribute__((ext_vector_type(4)));

__device__ __forceinline__ unsigned short f2bf(float f) {
    union { float f; unsigned u; } v; v.f = f;
    unsigned r = v.u + 0x7fffu + ((v.u >> 16) & 1u);   // RNE
    return (unsigned short)(r >> 16);
}

__device__ __forceinline__ void async16(const unsigned short* g, unsigned short* l) {
    __builtin_amdgcn_global_load_lds(
        (const __attribute__((address_space(1))) unsigned int*)(g),
        (__attribute__((address_space(3))) unsigned int*)(l),
        16, 0, 0);
}

// XOR-granule swizzle: pitch 64 shorts, 8-short (16B) granules, granule g of
// row r lives at slot g ^ (r&7).  All flash LDS b128 accesses are granule-
// aligned -> conflict-free.  Staging produces this layout via per-lane
// swizzled-ADDRESS async16 (LDS dest linear, src granule XOR'd) -- guide
// m173: the global source of global_load_lds IS per-lane.
__device__ __forceinline__ int swz64(int row, int col) {
    return (row << 6) + ((((col >> 3) ^ row) & 7) << 3) + (col & 7);
}

// ---------------------------------------------------------------------------
// fp32 -> bf16 conversion of x, Wq|Wk|Wv (packed), Wo.
// (R7 PM: fusing this into GEMM staging was 71.7us QKV vs <43 -- keep it.)
// ---------------------------------------------------------------------------
__global__ __launch_bounds__(256)
void convert_kernel(const float* __restrict__ x,
                    const float* __restrict__ wq, const float* __restrict__ wk,
                    const float* __restrict__ wv, const float* __restrict__ wo,
                    unsigned short* __restrict__ xb,
                    unsigned short* __restrict__ wqkvb,
                    unsigned short* __restrict__ wob)
{
    const unsigned e = (blockIdx.x * 256u + threadIdx.x) * 8u;
    const float* src; unsigned short* dst; unsigned off;
    if      (e < 4194304u) { src = x;  dst = xb;             off = e;            }
    else if (e < 5242880u) { src = wq; dst = wqkvb;          off = e - 4194304u; }
    else if (e < 6291456u) { src = wk; dst = wqkvb+1048576u; off = e - 5242880u; }
    else if (e < 7340032u) { src = wv; dst = wqkvb+2097152u; off = e - 6291456u; }
    else                   { src = wo; dst = wob;            off = e - 7340032u; }
    float4 a = *(const float4*)(src + off);
    float4 b = *(const float4*)(src + off + 4);
    ushort4 u0, u1;
    u0.x=f2bf(a.x); u0.y=f2bf(a.y); u0.z=f2bf(a.z); u0.w=f2bf(a.w);
    u1.x=f2bf(b.x); u1.y=f2bf(b.y); u1.z=f2bf(b.z); u1.w=f2bf(b.w);
    *(ushort4*)(dst + off)     = u0;
    *(ushort4*)(dst + off + 4) = u1;
}

// ---------------------------------------------------------------------------
// bf16 MFMA GEMM: Y = A[M][1024] @ B[NCOLS][1024]^T.  TM x TN tiles, BK=64,
// single-buffered async16 (m97 structure).  QKV: 128x128 @ 3/CU.
// O-proj: 128x64 @ 2/CU, MODE 0 (R8 PM: fused combine cost ~10us vs this).
// MODE 0: fp32 row-major out (O-proj).
// MODE 1 (QKV): cols <2048 -> RoPE (rotation recurrence) -> qk buf;
//   cols >=2048 -> V^T written PRE-PERMUTED: within each 64-col kt block,
//   col' = 16*((s>>2)&3) + 4*((s>>4)&3) + (s&3), so flash stages V with
//   linear-dest async16 + XOR'd source granule.
// ---------------------------------------------------------------------------
template<int TM, int TN, int NCOLS, int MODE, int MINW>
__global__ __launch_bounds__(256, MINW)
void gemm_mfma_bt(const unsigned short* __restrict__ A,
                  const unsigned short* __restrict__ B,
                  void* __restrict__ Yqk,
                  unsigned short* __restrict__ Yvt)
{
    constexpr int AINST = TM / 32;
    constexpr int BINST = TN / 32;
    constexpr int MT    = TM / 32;
    constexpr int NT    = TN / 32;

    __shared__ unsigned short As[TM * 64];
    __shared__ unsigned short Bs[TN * 64];

    const int t    = threadIdx.x;
    const int w    = t >> 6;
    const int lane = t & 63;
    const int lq   = lane >> 4;
    const int ln   = lane & 15;
    const int m0   = blockIdx.y * TM;
    const int n0   = blockIdx.x * TN;

    const int mrow0 = (w & 1) * (TM / 2);
    const int ncol0 = (w >> 1) * (TN / 2);

    const int srow  = w*8 + (lane >> 3);
    const int gslot = (lane & 7) ^ (lane >> 3);

    const unsigned short* gA[AINST]; unsigned short* lA[AINST];
    #pragma unroll
    for (int i = 0; i < AINST; ++i) {
        gA[i] = A + (size_t)(m0 + i*32 + srow) * 1024 + gslot*8;
        lA[i] = As + (i*32 + w*8) * 64;
    }
    const unsigned short* gB[BINST]; unsigned short* lB[BINST];
    #pragma unroll
    for (int i = 0; i < BINST; ++i) {
        gB[i] = B + (size_t)(n0 + i*32 + srow) * 1024 + gslot*8;
        lB[i] = Bs + (i*32 + w*8) * 64;
    }

    f32x4 acc[MT][NT];
    #pragma unroll
    for (int mt = 0; mt < MT; ++mt)
        #pragma unroll
        for (int nt = 0; nt < NT; ++nt)
            #pragma unroll
            for (int r = 0; r < 4; ++r) acc[mt][nt][r] = 0.0f;

    const int fsw = (ln & 7);

    for (int k0 = 0; k0 < 1024; k0 += 64) {
        __syncthreads();
        #pragma unroll
        for (int i = 0; i < AINST; ++i) async16(gA[i] + k0, lA[i]);
        #pragma unroll
        for (int i = 0; i < BINST; ++i) async16(gB[i] + k0, lB[i]);
        __syncthreads();
        #pragma unroll
        for (int kh = 0; kh < 2; ++kh) {
            const int g  = kh*4 + lq;
            const int ps = (g ^ fsw) * 8;
            bf16x8 af[MT], bf[NT];
            #pragma unroll
            for (int mt = 0; mt < MT; ++mt)
                af[mt] = *(const bf16x8*)&As[(mrow0 + mt*16 + ln)*64 + ps];
            #pragma unroll
            for (int nt = 0; nt < NT; ++nt)
                bf[nt] = *(const bf16x8*)&Bs[(ncol0 + nt*16 + ln)*64 + ps];
            #pragma unroll
            for (int mt = 0; mt < MT; ++mt)
                #pragma unroll
                for (int nt = 0; nt < NT; ++nt)
                    acc[mt][nt] = __builtin_amdgcn_mfma_f32_16x16x32_bf16(
                                      af[mt], bf[nt], acc[mt][nt], 0, 0, 0);
        }
    }

    if constexpr (MODE == 0) {
        float* Yf = (float*)Yqk;
        #pragma unroll
        for (int nt = 0; nt < NT; ++nt) {
            const int col = n0 + ncol0 + nt*16 + ln;
            #pragma unroll
            for (int mt = 0; mt < MT; ++mt) {
                const int row0 = m0 + mrow0 + mt*16 + lq*4;
                #pragma unroll
                for (int r = 0; r < 4; ++r)
                    Yf[(size_t)(row0 + r) * NCOLS + col] = acc[mt][nt][r];
            }
        }
    } else if (n0 < 2048) {
        // QK region: RoPE via rotation recurrence, bf16 row-major LD 2048
        unsigned short* Yb = (unsigned short*)Yqk;
        const float LOG_T = 9.210340371976184f / 32.0f;
        #pragma unroll
        for (int nt = 0; nt < NT; ++nt) {
            const int col = n0 + ncol0 + nt*16 + ln;
            const float fr = __expf(-(float)((col & 63) >> 1) * LOG_T);
            float sd, cd;
            __sincosf(fr, &sd, &cd);           // per-row rotation delta
            #pragma unroll
            for (int mt = 0; mt < MT; ++mt) {
                const int row0 = m0 + mrow0 + mt*16 + lq*4;
                float sn, cs;
                __sincosf((float)(row0 & (SEQ - 1)) * fr, &sn, &cs);
                #pragma unroll
                for (int r = 0; r < 4; ++r) {
                    const float v = acc[mt][nt][r];
                    const float p = __shfl_xor(v, 1);
                    const float outv = ((ln & 1) == 0) ? (v*cs - p*sn) : (p*sn + v*cs);
                    Yb[(size_t)(row0 + r) * 2048 + col] = f2bf(outv);
                    const float cs2 = cs*cd - sn*sd;   // rotate angle by fr
                    sn = sn*cd + cs*sd;
                    cs = cs2;
                }
            }
        }
    } else {
        // V region: V^T pre-permuted within each 64-col kt block
        #pragma unroll
        for (int nt = 0; nt < NT; ++nt) {
            const int d = (n0 - 2048) + ncol0 + nt*16 + ln;
            #pragma unroll
            for (int mt = 0; mt < MT; ++mt) {
                const int row0 = m0 + mrow0 + mt*16 + lq*4;
                const int b = row0 >> 11;
                const int s = row0 & 2047;
                const int sp = (s & ~63) + 16*((s >> 2) & 3) + 4*((s >> 4) & 3);
                ushort4 o;
                o.x = f2bf(acc[mt][nt][0]); o.y = f2bf(acc[mt][nt][1]);
                o.z = f2bf(acc[mt][nt][2]); o.w = f2bf(acc[mt][nt][3]);
                *(ushort4*)&Yvt[((size_t)b*1024 + d) * 2048 + sp] = o;
            }
        }
    }
}

// ---------------------------------------------------------------------------
// R20 flash: TWO q-tiles per block sharing one staged KV stream -- replaces
// the R13 split/partials/combine entirely.  Block (bh, j): q-tile A = 31-j,
// q-tile B = j.  KV loop kt = 0..31-j: A computes every iter, B only while
// kt <= j.  Per-block compute = (32-j)+(j+1) = 33 tile-computes, uniform.
// Both q-tiles finish in-block -> direct bf16 epilogue, no Opart/Lp.
// K/V/Q staged via per-lane swizzled-address async16 (zero staging VALU),
// double-buffered, ONE barrier per KV tile.  Max-free softmax.
// Grid (32,16) = 512 = 2/CU; bid%8 = bh%8 keeps each head's K/V on 1 XCD L2.
// ---------------------------------------------------------------------------
__global__ __launch_bounds__(256, 2)
void flash_mfma_kernel(const unsigned short* __restrict__ QK,
                       const unsigned short* __restrict__ Vtg,
                       unsigned short* __restrict__ Ob)
{
    __shared__ unsigned short Kt[2 * 64 * 64];   // dbuf: K tiles (buf1 = QA pre)
    __shared__ unsigned short Vt[2 * 64 * 64];   // dbuf: V^T tiles (buf1 = QB pre)

    const int t    = threadIdx.x;
    const int w    = t >> 6;
    const int lane = t & 63;
    const int lq   = lane >> 4;
    const int ln   = lane & 15;
    const int bh   = blockIdx.x;
    const int j    = blockIdx.y;       // pair index 0..15
    const int b    = bh >> 4;
    const int hd   = bh & 15;
    const int qA   = 31 - j;
    const int qB   = j;

    const unsigned short* Kgb = QK + 1024 + hd*DK + (size_t)b*SEQ*2048;  // LD 2048
    const unsigned short* Vgb = Vtg + ((size_t)b*1024 + hd*DK) * 2048;   // [d][s']
    const unsigned short* QgA = QK + hd*DK + (size_t)(b*SEQ + qA*64)*2048;
    const unsigned short* QgB = QK + hd*DK + (size_t)(b*SEQ + qB*64)*2048;

    const int r0 = w*8 + (lane >> 3);          // staging row (0..31)
    const int r1 = 32 + r0;                    // staging row (32..63)
    const int sl = lane & 7;                   // linear LDS slot
    const int g0 = (sl ^ r0) & 7;              // swizzled source granule
    const int g1 = (sl ^ r1) & 7;
    const float SCALE2 = 0.125f * 1.4426950408889634f;   // 1/sqrt(dk) * log2e

    unsigned short* ldKLo = Kt + (w*8)*64;     // wave-uniform LDS bases
    unsigned short* ldKHi = Kt + (32 + w*8)*64;
    unsigned short* ldVLo = Vt + (w*8)*64;
    unsigned short* ldVHi = Vt + (32 + w*8)*64;

    // prologue: QA -> Kt buf1, QB -> Vt buf1, K/V tile 0 -> buf0
    async16(QgA + (size_t)r0*2048 + g0*8, ldKLo + KBUF);
    async16(QgA + (size_t)r1*2048 + g1*8, ldKHi + KBUF);
    async16(QgB + (size_t)r0*2048 + g0*8, ldVLo + KBUF);
    async16(QgB + (size_t)r1*2048 + g1*8, ldVHi + KBUF);
    async16(Kgb + (size_t)r0*2048 + g0*8, ldKLo);
    async16(Kgb + (size_t)r1*2048 + g1*8, ldKHi);
    async16(Vgb + (size_t)r0*2048 + g0*8, ldVLo);
    async16(Vgb + (size_t)r1*2048 + g1*8, ldVHi);
    __syncthreads();                           // all async16 drained
    const bf16x8 qfA0 = *(const bf16x8*)&Kt[KBUF + swz64(w*16 + ln, lq*8)];
    const bf16x8 qfA1 = *(const bf16x8*)&Kt[KBUF + swz64(w*16 + ln, 32 + lq*8)];
    const bf16x8 qfB0 = *(const bf16x8*)&Vt[KBUF + swz64(w*16 + ln, lq*8)];
    const bf16x8 qfB1 = *(const bf16x8*)&Vt[KBUF + swz64(w*16 + ln, 32 + lq*8)];

    f32x4 oaccA[4], oaccB[4];
    #pragma unroll
    for (int dt = 0; dt < 4; ++dt)
        #pragma unroll
        for (int r = 0; r < 4; ++r) { oaccA[dt][r] = 0.0f; oaccB[dt][r] = 0.0f; }
    float lA = 0.0f, lB = 0.0f;
    const int qgA = qA*64 + w*16 + ln;
    const int qgB = qB*64 + w*16 + ln;

    __syncthreads();                           // qf reads drained

    int cur = 0;
    for (int kt = 0; kt <= qA; ++kt) {
        const int co = cur ? KBUF : 0;
        const int no = co ^ KBUF;

        if (kt < qA) {    // stage kt+1 -> other buffer; drains under compute
            async16(Kgb + (size_t)((kt+1)*64 + r0)*2048 + g0*8, ldKLo + no);
            async16(Kgb + (size_t)((kt+1)*64 + r1)*2048 + g1*8, ldKHi + no);
            async16(Vgb + (size_t)r0*2048 + (kt+1)*64 + g0*8, ldVLo + no);
            async16(Vgb + (size_t)r1*2048 + (kt+1)*64 + g1*8, ldVHi + no);
        }

        // K frags (shared by A and B)
        bf16x8 kf0[4], kf1[4];
        #pragma unroll
        for (int nt = 0; nt < 4; ++nt) {
            kf0[nt] = *(const bf16x8*)&Kt[co + swz64(nt*16 + ln, lq*8)];
            kf1[nt] = *(const bf16x8*)&Kt[co + swz64(nt*16 + ln, 32 + lq*8)];
        }
        // V frags (shared by A and B)
        union { bf16x8 v8; s16x4 h2[2]; } u01[4], u23[4];
        #pragma unroll
        for (int dt = 0; dt < 4; ++dt) {
            u01[dt].v8 = *(const bf16x8*)&Vt[co + swz64(dt*16 + ln, lq*16)];
            u23[dt].v8 = *(const bf16x8*)&Vt[co + swz64(dt*16 + ln, lq*16 + 8)];
        }

        // ---- q-tile A (always) ----
        {
            f32x4 sacc[4];
            #pragma unroll
            for (int nt = 0; nt < 4; ++nt) {
                #pragma unroll
                for (int r = 0; r < 4; ++r) sacc[nt][r] = 0.0f;
                sacc[nt] = __builtin_amdgcn_mfma_f32_16x16x32_bf16(kf0[nt], qfA0, sacc[nt], 0, 0, 0);
                sacc[nt] = __builtin_amdgcn_mfma_f32_16x16x32_bf16(kf1[nt], qfA1, sacc[nt], 0, 0, 0);
            }
            float p[16];
            if (kt == qA) {
                #pragma unroll
                for (int nt = 0; nt < 4; ++nt)
                    #pragma unroll
                    for (int r = 0; r < 4; ++r) {
                        float s = fminf(sacc[nt][r] * SCALE2, 50.0f);
                        if (kt*64 + nt*16 + lq*4 + r > qgA) s = -INFINITY;
                        p[nt*4 + r] = __builtin_amdgcn_exp2f(s);
                    }
            } else {
                #pragma unroll
                for (int i2 = 0; i2 < 16; ++i2) {
                    const int nt = i2 >> 2, r = i2 & 3;
                    p[i2] = __builtin_amdgcn_exp2f(fminf(sacc[nt][r] * SCALE2, 50.0f));
                }
            }
            float sum = 0.0f;
            #pragma unroll
            for (int i2 = 0; i2 < 16; ++i2) sum += p[i2];
            lA += sum;
            s16x4 pf[4];
            #pragma unroll
            for (int kk = 0; kk < 4; ++kk) {
                union { float f; unsigned u; } c0, c1, c2, c3;
                c0.f = p[kk*4+0]; c1.f = p[kk*4+1]; c2.f = p[kk*4+2]; c3.f = p[kk*4+3];
                unsigned lo = __builtin_amdgcn_perm(c1.u + 0x8000u, c0.u + 0x8000u, 0x07060302u);
                unsigned hi = __builtin_amdgcn_perm(c3.u + 0x8000u, c2.u + 0x8000u, 0x07060302u);
                union { unsigned u2[2]; s16x4 v; } pk;
                pk.u2[0] = lo; pk.u2[1] = hi;
                pf[kk] = pk.v;
            }
            #pragma unroll
            for (int dt = 0; dt < 4; ++dt) {
                oaccA[dt] = __builtin_amdgcn_mfma_f32_16x16x16bf16_1k(u01[dt].h2[0], pf[0], oaccA[dt], 0, 0, 0);
                oaccA[dt] = __builtin_amdgcn_mfma_f32_16x16x16bf16_1k(u01[dt].h2[1], pf[1], oaccA[dt], 0, 0, 0);
                oaccA[dt] = __builtin_amdgcn_mfma_f32_16x16x16bf16_1k(u23[dt].h2[0], pf[2], oaccA[dt], 0, 0, 0);
                oaccA[dt] = __builtin_amdgcn_mfma_f32_16x16x16bf16_1k(u23[dt].h2[1], pf[3], oaccA[dt], 0, 0, 0);
            }
        }

        // ---- q-tile B (while kt <= qB; block-uniform branch) ----
        if (kt <= qB) {
            f32x4 sacc[4];
            #pragma unroll
            for (int nt = 0; nt < 4; ++nt) {
                #pragma unroll
                for (int r = 0; r < 4; ++r) sacc[nt][r] = 0.0f;
                sacc[nt] = __builtin_amdgcn_mfma_f32_16x16x32_bf16(kf0[nt], qfB0, sacc[nt], 0, 0, 0);
                sacc[nt] = __builtin_amdgcn_mfma_f32_16x16x32_bf16(kf1[nt], qfB1, sacc[nt], 0, 0, 0);
            }
            float p[16];
            if (kt == qB) {
                #pragma unroll
                for (int nt = 0; nt < 4; ++nt)
                    #pragma unroll
                    for (int r = 0; r < 4; ++r) {
                        float s = fminf(sacc[nt][r] * SCALE2, 50.0f);
                        if (kt*64 + nt*16 + lq*4 + r > qgB) s = -INFINITY;
                        p[nt*4 + r] = __builtin_amdgcn_exp2f(s);
                    }
            } else {
                #pragma unroll
                for (int i2 = 0; i2 < 16; ++i2) {
                    const int nt = i2 >> 2, r = i2 & 3;
                    p[i2] = __builtin_amdgcn_exp2f(fminf(sacc[nt][r] * SCALE2, 50.0f));
                }
            }
            float sum = 0.0f;
            #pragma unroll
            for (int i2 = 0; i2 < 16; ++i2) sum += p[i2];
            lB += sum;
            s16x4 pf[4];
            #pragma unroll
            for (int kk = 0; kk < 4; ++kk) {
                union { float f; unsigned u; } c0, c1, c2, c3;
                c0.f = p[kk*4+0]; c1.f = p[kk*4+1]; c2.f = p[kk*4+2]; c3.f = p[kk*4+3];
                unsigned lo = __builtin_amdgcn_perm(c1.u + 0x8000u, c0.u + 0x8000u, 0x07060302u);
                unsigned hi = __builtin_amdgcn_perm(c3.u + 0x8000u, c2.u + 0x8000u, 0x07060302u);
                union { unsigned u2[2]; s16x4 v; } pk;
                pk.u2[0] = lo; pk.u2[1] = hi;
                pf[kk] = pk.v;
            }
            #pragma unroll
            for (int dt = 0; dt < 4; ++dt) {
                oaccB[dt] = __builtin_amdgcn_mfma_f32_16x16x16bf16_1k(u01[dt].h2[0], pf[0], oaccB[dt], 0, 0, 0);
                oaccB[dt] = __builtin_amdgcn_mfma_f32_16x16x16bf16_1k(u01[dt].h2[1], pf[1], oaccB[dt], 0, 0, 0);
                oaccB[dt] = __builtin_amdgcn_mfma_f32_16x16x16bf16_1k(u23[dt].h2[0], pf[2], oaccB[dt], 0, 0, 0);
                oaccB[dt] = __builtin_amdgcn_mfma_f32_16x16x16bf16_1k(u23[dt].h2[1], pf[3], oaccB[dt], 0, 0, 0);
            }
        }

        __syncthreads();    // buf[no] async writes visible; buf[cur] drained
        cur ^= 1;
    }

    // ---- epilogue: reduce l across quads, normalize, transpose, store ----
    lA += __shfl_xor(lA, 16);  lA += __shfl_xor(lA, 32);
    lB += __shfl_xor(lB, 16);  lB += __shfl_xor(lB, 32);
    const float liA = 1.0f / lA;
    const float liB = 1.0f / lB;
    // loop's final barrier drained all buf reads -> Kt/Vt reusable
    #pragma unroll
    for (int dt = 0; dt < 4; ++dt)
        #pragma unroll
        for (int r = 0; r < 4; ++r) {
            Kt[swz64(w*16 + ln, dt*16 + lq*4 + r)] = f2bf(oaccA[dt][r] * liA);
            Vt[swz64(w*16 + ln, dt*16 + lq*4 + r)] = f2bf(oaccB[dt][r] * liB);
        }
    __syncthreads();
    const int sr  = t >> 2;
    const int sc2 = (t & 3) * 16;
    unsigned short* opA = Ob + (size_t)(b*SEQ + qA*64 + sr) * DMODEL + hd*DK + sc2;
    *(float4*)(opA)     = *(const float4*)&Kt[swz64(sr, sc2)];
    *(float4*)(opA + 8) = *(const float4*)&Kt[swz64(sr, sc2 + 8)];
    unsigned short* opB = Ob + (size_t)(b*SEQ + qB*64 + sr) * DMODEL + hd*DK + sc2;
    *(float4*)(opB)     = *(const float4*)&Vt[swz64(sr, sc2)];
    *(float4*)(opB + 8) = *(const float4*)&Vt[swz64(sr, sc2 + 8)];
}

// ---------------------------------------------------------------------------
extern "C" void kernel_launch(void* const* d_in, const int* in_sizes, int n_in,
                              void* d_out, int out_size, void* d_ws, size_t ws_size,
                              hipStream_t stream)
{
    const float* x  = (const float*)d_in[0];
    const float* Wq = (const float*)d_in[1];
    const float* Wk = (const float*)d_in[2];
    const float* Wv = (const float*)d_in[3];
    const float* Wo = (const float*)d_in[4];
    float* out = (float*)d_out;

    unsigned short* xb    = (unsigned short*)d_ws;   //  4M shorts
    unsigned short* wqkvb = xb + 4194304;            //  3M
    unsigned short* wob   = wqkvb + 3145728;         //  1M
    unsigned short* qk    = wob + 1048576;           //  8M  [4096][2048]
    unsigned short* vt    = qk + 8388608;            //  4M  [2][1024][2048] perm
    unsigned short* ob    = vt + 4194304;            //  4M  [4096][1024]
    // total 48 MB; no partials/combine (R20)

    convert_kernel<<<4096, 256, 0, stream>>>(x, Wq, Wk, Wv, Wo, xb, wqkvb, wob);

    // QKV: 128x128 tiles, grid (24,32) = 768 blocks = 3/CU
    gemm_mfma_bt<128, 128, 2048, 1, 3><<<dim3(24, 32), 256, 0, stream>>>(
        xb, wqkvb, qk, vt);

    // R20 flash: 2 q-tiles/block, 32 bh x 16 pairs = 512 blocks = 2/CU
    flash_mfma_kernel<<<dim3(32, 16), 256, 0, stream>>>(qk, vt, ob);

    // O-proj: 128x64 tiles, (16,32) = 512 blocks = 2/CU, MODE 0
    gemm_mfma_bt<128, 64, 1024, 0, 2><<<dim3(16, 32), 256, 0, stream>>>(
        ob, wob, out, nullptr);
}